// Round 15
// baseline (275.992 us; speedup 1.0000x reference)
//
#include <hip/hip_runtime.h>

#define T_STEPS 301
#define IN_DIM  40
#define LOG2E   1.44269504088896340736f

typedef __attribute__((ext_vector_type(8))) _Float16 f16x8;
typedef __attribute__((ext_vector_type(4))) float f32x4;
typedef unsigned short ushort_t;
typedef unsigned int uint_t;

union u16cv { _Float16 hf; ushort_t u; };

#define MFMA16(A, B, C) __builtin_amdgcn_mfma_f32_16x16x32_f16((A), (B), (C), 0, 0, 0)

__device__ __forceinline__ f16x8 cvt8h(const float4 a, const float4 b) {
  f16x8 r;
  r[0] = (_Float16)a.x; r[1] = (_Float16)a.y; r[2] = (_Float16)a.z; r[3] = (_Float16)a.w;
  r[4] = (_Float16)b.x; r[5] = (_Float16)b.y; r[6] = (_Float16)b.z; r[7] = (_Float16)b.w;
  return r;
}

// z pre-scaled by log2e (2*log2e for g-gate) -> exp2-based activations.
__device__ __forceinline__ float lstm_act(float zi, float zf, float zg, float zo, float& cc) {
  const float ig = __builtin_amdgcn_rcpf(1.0f + __builtin_amdgcn_exp2f(-zi));
  const float fg = __builtin_amdgcn_rcpf(1.0f + __builtin_amdgcn_exp2f(-zf));
  const float gg = 1.0f - 2.0f * __builtin_amdgcn_rcpf(1.0f + __builtin_amdgcn_exp2f(zg));
  const float og = __builtin_amdgcn_rcpf(1.0f + __builtin_amdgcn_exp2f(-zo));
  cc = fg * cc + ig * gg;
  const float tc = 1.0f - 2.0f * __builtin_amdgcn_rcpf(1.0f + __builtin_amdgcn_exp2f(cc * (2.0f * LOG2E)));
  return og * tc;
}

// 256 blocks x 512 thr (8 waves), 1 block/CU -> 2 waves/SIMD with independent
// progress between barriers. Waves w and w+4 run IDENTICAL MFMA volleys
// (zero-waste M=16, R13 structure; MFMA pipe has headroom) but SPLIT the
// activations: wave u = wv>>2 activates states r in {2u, 2u+1} only (20 trans
// instead of 40) and writes its 2 h rows. Wave A's act-chain stalls are filled
// by wave B's MFMA/VALU issue. VGPR<=128 (launch_bounds 512,2): wih B-frags in
// LDS (per-step lane-indexed b128 reads, loop-invariant addrs), whh in regs.
// Bias via k=40 input channel; wclf staged in LDS; XOR-swizzled h exchange.
__global__ __launch_bounds__(512, 2)
void lstm_d2(const float* __restrict__ x, const float* __restrict__ w_ih,
             const float* __restrict__ w_hh, const float* __restrict__ b_ih,
             const float* __restrict__ b_hh, const float* __restrict__ w_clf,
             const float* __restrict__ b_clf, float* __restrict__ out) {
  extern __shared__ char smem[];
  float*    wclf  = (float*)smem;                          // [301][64], 77056 B
  f16x8*    wihl  = (f16x8*)(smem + 77056);                // [(st*4+g)*2+kc][64], 32768 B
  ushort_t* hflat = (ushort_t*)(smem + 77056 + 32768);     // [2][16][64], 4096 B
  float*    red   = (float*)(smem + 77056 + 32768 + 4096); // [8][16], 512 B

  const int tid = threadIdx.x;
  const int l = tid & 63, wv = tid >> 6;
  const int strip = wv & 3, u = wv >> 2;
  const int c15 = l & 15, g16 = l >> 4;
  const int n = strip * 16 + c15;
  const int b0 = blockIdx.x * 16;
  const float gsc[4] = {LOG2E, LOG2E, 2.0f * LOG2E, LOG2E};

  // ---- stage wclf; zero h buffers and red ----
  for (int i = tid; i < (T_STEPS * 64) / 4; i += 512)
    ((float4*)wclf)[i] = ((const float4*)w_clf)[i];
  for (int i = tid; i < 1024; i += 512) ((uint_t*)hflat)[i] = 0;
  if (tid < 128) red[tid] = 0.f;

  // ---- stage wih (+bias via k=40) into LDS ----
  for (int idx = tid; idx < 2048; idx += 512) {
    const int l2 = idx & 63;
    const int kc = (idx >> 6) & 1;
    const int g  = (idx >> 7) & 3;
    const int st = idx >> 9;
    const int nn = st * 16 + (l2 & 15);
    const int kg = l2 >> 4;
    const float s = gsc[g];
    const float* wi = w_ih + (size_t)(g * 64 + nn) * IN_DIM;
    float4 v0 = make_float4(0, 0, 0, 0), v1 = make_float4(0, 0, 0, 0);
    if (kc == 0) {                       // k = 8*kg .. +7  (<= 31)
      v0 = *(const float4*)(wi + kg * 8);
      v1 = *(const float4*)(wi + kg * 8 + 4);
      v0.x *= s; v0.y *= s; v0.z *= s; v0.w *= s;
      v1.x *= s; v1.y *= s; v1.z *= s; v1.w *= s;
    } else if (kg == 0) {                // k = 32..39
      v0 = *(const float4*)(wi + 32);
      v1 = *(const float4*)(wi + 36);
      v0.x *= s; v0.y *= s; v0.z *= s; v0.w *= s;
      v1.x *= s; v1.y *= s; v1.z *= s; v1.w *= s;
    } else if (kg == 1) {                // k = 40: bias channel
      v0.x = (b_ih[g * 64 + nn] + b_hh[g * 64 + nn]) * s;
    }
    wihl[idx] = cvt8h(v0, v1);
  }

  // ---- whh in registers (fp16, prescaled) ----
  f16x8 whh[4][2];
#pragma unroll
  for (int g = 0; g < 4; ++g) {
    const float s = gsc[g];
    const float* wr = w_hh + (size_t)(g * 64 + n) * 64;
#pragma unroll
    for (int kc = 0; kc < 2; ++kc) {
      float4 v0 = *(const float4*)(wr + kc * 32 + g16 * 8);
      float4 v1 = *(const float4*)(wr + kc * 32 + g16 * 8 + 4);
      v0.x *= s; v0.y *= s; v0.z *= s; v0.w *= s;
      v1.x *= s; v1.y *= s; v1.z *= s; v1.w *= s;
      whh[g][kc] = cvt8h(v0, v1);
    }
  }
  __syncthreads();   // staging visible

  // ---- loop-invariant LDS indices (R13 layout) ----
  const int akey = (c15 >> 2) << 4;
  const int ridx0 = c15 * 64 + ((8 * g16) ^ akey);
  const int ridx1 = c15 * 64 + ((32 + 8 * g16) ^ akey);
  const int r0 = 2 * u, r1 = 2 * u + 1;       // this wave's act states
  const int widx0 = (4 * g16 + r0) * 64 + (n ^ (g16 << 4));
  const int widx1 = (4 * g16 + r1) * 64 + (n ^ (g16 << 4));
  const f16x8* const wbase = &wihl[(strip * 4) * 2 * 64 + l];   // + (g*2+kc)*64

  // ---- x A-side (row = batch c15, k = 8*g16..) ----
  const float* xb = x + (size_t)(b0 + c15) * T_STEPS * IN_DIM;
  float4 px0 = *(const float4*)(xb + g16 * 8);
  float4 px1 = *(const float4*)(xb + g16 * 8 + 4);
  float4 pq0 = make_float4(0, 0, 0, 0), pq1 = make_float4(0, 0, 0, 0);
  if (g16 == 0) {
    pq0 = *(const float4*)(xb + 32);
    pq1 = *(const float4*)(xb + 36);
  }
  f16x8 xf1c = {};
  if (g16 == 1) xf1c[0] = (_Float16)1.0f;     // k=40 bias multiplier

  f32x4 z[4];
  float cc0 = 0.f, cc1 = 0.f, acl0 = 0.f, acl1 = 0.f;

  for (int t = 0; t < T_STEPS; ++t) {
    const int rb = (t & 1) * 1024, wb2 = 1024 - rb;

    // issue h A-frag reads first
    f16x8 a0 = *(const f16x8*)(hflat + rb + ridx0);
    f16x8 a1 = *(const f16x8*)(hflat + rb + ridx1);

    // xproj: z = x[t] @ wih^T (+bias), wih frags streamed from LDS
    f16x8 xf0 = cvt8h(px0, px1);
    f16x8 xf1 = xf1c;
    if (g16 == 0) xf1 = cvt8h(pq0, pq1);
#pragma unroll
    for (int g = 0; g < 4; ++g) {
      const f16x8 w0 = wbase[(g * 2 + 0) * 64];
      const f16x8 w1 = wbase[(g * 2 + 1) * 64];
      f32x4 zz = {0.f, 0.f, 0.f, 0.f};
      zz = MFMA16(xf0, w0, zz);
      z[g] = MFMA16(xf1, w1, zz);
    }

    // prefetch next step's x
    {
      const int tn = (t + 1 < T_STEPS) ? t + 1 : t;
      const float* xp = xb + (size_t)tn * IN_DIM;
      px0 = *(const float4*)(xp + g16 * 8);
      px1 = *(const float4*)(xp + g16 * 8 + 4);
      if (g16 == 0) {
        pq0 = *(const float4*)(xp + 32);
        pq1 = *(const float4*)(xp + 36);
      }
    }

    // recurrence: z += h[t-1] @ whh^T
#pragma unroll
    for (int g = 0; g < 4; ++g) {
      z[g] = MFMA16(a0, whh[g][0], z[g]);
      z[g] = MFMA16(a1, whh[g][1], z[g]);
    }

    // activations: this wave's 2 states only (wave-uniform branch,
    // compile-time z indices in each arm)
    const float wc = wclf[t * 64 + n];
    float h0, h1;
    if (u == 0) {
      h0 = lstm_act(z[0][0], z[1][0], z[2][0], z[3][0], cc0);
      h1 = lstm_act(z[0][1], z[1][1], z[2][1], z[3][1], cc1);
    } else {
      h0 = lstm_act(z[0][2], z[1][2], z[2][2], z[3][2], cc0);
      h1 = lstm_act(z[0][3], z[1][3], z[2][3], z[3][3], cc1);
    }
    acl0 += h0 * wc;
    acl1 += h1 * wc;
    u16cv cv0, cv1;
    cv0.hf = (_Float16)h0;
    cv1.hf = (_Float16)h1;
    hflat[wb2 + widx0] = cv0.u;
    hflat[wb2 + widx1] = cv1.u;

    asm volatile("s_waitcnt lgkmcnt(0)\n\ts_barrier" ::: "memory");
  }

  // ---- epilogue: reduce over c15 lanes, then across waves via red ----
#pragma unroll
  for (int m = 1; m <= 8; m <<= 1) {
    acl0 += __shfl_xor(acl0, m);
    acl1 += __shfl_xor(acl1, m);
  }
  if (c15 == 0) {
    red[wv * 16 + 4 * g16 + r0] = acl0;
    red[wv * 16 + 4 * g16 + r1] = acl1;
  }
  __syncthreads();
  if (tid < 16) {
    float s = b_clf[0];
#pragma unroll
    for (int w2 = 0; w2 < 8; ++w2) s += red[w2 * 16 + tid];
    out[b0 + tid] = s;
  }
}

extern "C" void kernel_launch(void* const* d_in, const int* in_sizes, int n_in,
                              void* d_out, int out_size, void* d_ws, size_t ws_size,
                              hipStream_t stream) {
  const float* x     = (const float*)d_in[0];
  const float* w_ih  = (const float*)d_in[1];
  const float* w_hh  = (const float*)d_in[2];
  const float* b_ih  = (const float*)d_in[3];
  const float* b_hh  = (const float*)d_in[4];
  const float* w_clf = (const float*)d_in[5];
  const float* b_clf = (const float*)d_in[6];
  float* out = (float*)d_out;

  const size_t shmem = 77056 + 32768 + 4096 + 512;   // ~111.8 KB dynamic LDS
  (void)hipFuncSetAttribute((const void*)lstm_d2,
                            hipFuncAttributeMaxDynamicSharedMemorySize, (int)shmem);
  lstm_d2<<<256, 512, shmem, stream>>>(x, w_ih, w_hh, b_ih, b_hh, w_clf, b_clf, out);
}

// Round 16
// 191.142 us; speedup vs baseline: 1.4439x; 1.4439x over previous
//
#include <hip/hip_runtime.h>

#define T_STEPS 301
#define IN_DIM  40
#define LOG2E   1.44269504088896340736f

typedef __attribute__((ext_vector_type(8))) _Float16 f16x8;
typedef __attribute__((ext_vector_type(4))) float f32x4;
typedef unsigned short ushort_t;
typedef unsigned int uint_t;

__device__ __forceinline__ f16x8 cvt8h(const float4 a, const float4 b) {
  f16x8 r;
  r[0] = (_Float16)a.x; r[1] = (_Float16)a.y; r[2] = (_Float16)a.z; r[3] = (_Float16)a.w;
  r[4] = (_Float16)b.x; r[5] = (_Float16)b.y; r[6] = (_Float16)b.z; r[7] = (_Float16)b.w;
  return r;
}

// z inputs pre-scaled by log2e (2*log2e for g-gate) -> exp2-based activations.
__device__ __forceinline__ float lstm_act(float zi, float zf, float zg, float zo, float& cc) {
  const float ig = __builtin_amdgcn_rcpf(1.0f + __builtin_amdgcn_exp2f(-zi));
  const float fg = __builtin_amdgcn_rcpf(1.0f + __builtin_amdgcn_exp2f(-zf));
  const float gg = 1.0f - 2.0f * __builtin_amdgcn_rcpf(1.0f + __builtin_amdgcn_exp2f(zg));
  const float og = __builtin_amdgcn_rcpf(1.0f + __builtin_amdgcn_exp2f(-zo));
  cc = fg * cc + ig * gg;
  const float tc = 1.0f - 2.0f * __builtin_amdgcn_rcpf(1.0f + __builtin_amdgcn_exp2f(cc * (2.0f * LOG2E)));
  return og * tc;
}

// R16 = R8 (proven 191us: 1024 blocks x 256 thr, 4 blocks/CU, q=4 time-pack,
// XOR-swizzled hbuf, wih in LDS, no spill) + PHASE STAGGER: co-resident blocks
// start offset by ~384 cyc each (s_sleep) to break the barrier phase-lock that
// makes N identical co-scheduled chains behave like 1 (R6/R8/R13 all measured
// ~1000 states per ~1500 cyc/CU regardless of chains/SIMD). Single-variable
// experiment vs R8.
__global__ __launch_bounds__(256, 4)
void lstm_q4t(const float* __restrict__ x, const float* __restrict__ w_ih,
              const float* __restrict__ w_hh, const float* __restrict__ b_ih,
              const float* __restrict__ b_hh, const float* __restrict__ w_clf,
              const float* __restrict__ b_clf, float* __restrict__ out) {
  __shared__ f16x8 wlds[4][4][2][64];    // 32 KB: per-wave wih B-frags
  __shared__ ushort_t hbuf[2][16][64];   // 4 KB: fp16 h, XOR-swizzled chunks
  __shared__ float red[64][5];

  const int tid = threadIdx.x;
  const int l   = tid & 63;
  const int w   = tid >> 6;        // n-strip id (wave)
  const int r15 = l & 15;          // A/D-row role; D-col role
  const int g16 = l >> 4;          // k-group role; D row-group = BATCH
  const int n   = w * 16 + r15;    // hidden index

  const float gscale[4] = {LOG2E, LOG2E, 2.0f * LOG2E, LOG2E};

  // ---- whh B-frags in registers; wih B-frags into LDS (read 1x per pack) ----
  f16x8 whh[4][2];
  float biasv[4];
#pragma unroll
  for (int c = 0; c < 4; ++c) {
    const float s = gscale[c];
    const float* wr = w_hh + (size_t)(c * 64 + n) * 64;
#pragma unroll
    for (int kc = 0; kc < 2; ++kc) {
      float4 v0 = *(const float4*)(wr + kc * 32 + g16 * 8);
      float4 v1 = *(const float4*)(wr + kc * 32 + g16 * 8 + 4);
      v0.x *= s; v0.y *= s; v0.z *= s; v0.w *= s;
      v1.x *= s; v1.y *= s; v1.z *= s; v1.w *= s;
      whh[c][kc] = cvt8h(v0, v1);
    }
    const float* wir = w_ih + (size_t)(c * 64 + n) * IN_DIM;
    {
      float4 v0 = *(const float4*)(wir + g16 * 8);   // k = 8*g16..+8 <= 31
      float4 v1 = *(const float4*)(wir + g16 * 8 + 4);
      v0.x *= s; v0.y *= s; v0.z *= s; v0.w *= s;
      v1.x *= s; v1.y *= s; v1.z *= s; v1.w *= s;
      wlds[w][c][0][l] = cvt8h(v0, v1);
    }
    {
      float4 v0 = make_float4(0, 0, 0, 0), v1 = make_float4(0, 0, 0, 0);
      if (g16 == 0) {                                // k = 32..39
        v0 = *(const float4*)(wir + 32);
        v1 = *(const float4*)(wir + 36);
        v0.x *= s; v0.y *= s; v0.z *= s; v0.w *= s;
        v1.x *= s; v1.y *= s; v1.z *= s; v1.w *= s;
      }
      wlds[w][c][1][l] = cvt8h(v0, v1);
    }
    biasv[c] = (b_ih[c * 64 + n] + b_hh[c * 64 + n]) * s;
  }

  // zero both h buffers
  {
    uint_t* hz = (uint_t*)&hbuf[0][0][0];
    for (int i = tid; i < 1024; i += 256) hz[i] = 0;
  }
  __syncthreads();

  // ---- phase stagger: offset co-resident blocks ~1/4 step each ----
  {
    const int ph = (int)((blockIdx.x + (blockIdx.x >> 8)) & 3u);
    if (ph > 0) __builtin_amdgcn_s_sleep(6);   // ~384 cyc
    if (ph > 1) __builtin_amdgcn_s_sleep(6);
    if (ph > 2) __builtin_amdgcn_s_sleep(6);
  }

  // x A-provider mapping: lane provides A row r15 = 4*s_a + q_a
  const int s_a = r15 >> 2;
  const int q_a = r15 & 3;
  const float* xbase = x + (size_t)(blockIdx.x * 4 + s_a) * T_STEPS * IN_DIM;

  float4 xa0, xa1, xb0 = make_float4(0, 0, 0, 0), xb1 = make_float4(0, 0, 0, 0);
  {
    const float* xp = xbase + q_a * IN_DIM + g16 * 8;
    xa0 = *(const float4*)xp;
    xa1 = *(const float4*)(xp + 4);
    if (g16 == 0) {
      xb0 = *(const float4*)(xbase + q_a * IN_DIM + 32);
      xb1 = *(const float4*)(xbase + q_a * IN_DIM + 36);
    }
  }

  f32x4 zacc[4];
  float cc = 0.f, a = 0.f;
  float wc_cur = w_clf[n];
  const int wrb = g16 * 4;

  // loop-invariant swizzled LDS addresses
  ushort_t* const hflat = &hbuf[0][0][0];
  const int rsw = r15 & 7;
  const f16x8* const rb0k0 = (const f16x8*)&hflat[       r15 * 64 + ((g16    ) ^ rsw) * 8];
  const f16x8* const rb0k1 = (const f16x8*)&hflat[       r15 * 64 + ((g16 + 4) ^ rsw) * 8];
  const f16x8* const rb1k0 = (const f16x8*)&hflat[1024 + r15 * 64 + ((g16    ) ^ rsw) * 8];
  const f16x8* const rb1k1 = (const f16x8*)&hflat[1024 + r15 * 64 + ((g16 + 4) ^ rsw) * 8];
  const int nc = n >> 3, ne = n & 7;
#define WIDX(BUF, R) ((BUF) * 1024 + (R) * 64 + ((nc ^ ((R) & 7)) * 8) + ne)
  const int w_q0 = WIDX(1, wrb + 1), z_q0 = WIDX(1, wrb + 3);
  const int w_q1 = WIDX(0, wrb + 2), z_q1 = WIDX(0, wrb + 0);
  const int w_q2 = WIDX(1, wrb + 3), z_q2 = WIDX(1, wrb + 1);
  const int w_q3 = WIDX(0, wrb + 0), z_q3 = WIDX(0, wrb + 2);
#undef WIDX

#define QSTEP(Q, PK0, PK1, WI, ZI)                                                \
  {                                                                               \
    const int t = t0 + Q;                                                         \
    f16x8 ah0 = *(PK0);                                                           \
    f16x8 ah1 = *(PK1);                                                           \
    _Pragma("unroll")                                                             \
    for (int c = 0; c < 4; ++c) {                                                 \
      zacc[c] = __builtin_amdgcn_mfma_f32_16x16x32_f16(ah0, whh[c][0], zacc[c], 0, 0, 0); \
      zacc[c] = __builtin_amdgcn_mfma_f32_16x16x32_f16(ah1, whh[c][1], zacc[c], 0, 0, 0); \
    }                                                                             \
    const float wcn = (t + 1 < T_STEPS) ? w_clf[(t + 1) * 64 + n] : wc_cur;       \
    const float h = lstm_act(zacc[0][Q], zacc[1][Q], zacc[2][Q], zacc[3][Q], cc); \
    a += h * wc_cur;                                                              \
    wc_cur = wcn;                                                                 \
    union { _Float16 hf; ushort_t u; } cv;                                        \
    cv.hf = (_Float16)h;                                                          \
    hflat[WI] = cv.u;                                                             \
    hflat[ZI] = 0;                                                                \
    asm volatile("s_waitcnt lgkmcnt(0)\n\ts_barrier" ::: "memory");               \
  }

  for (int p = 0; p <= 75; ++p) {
    const int t0 = 4 * p;
    // ---- q = 0: xproj volley (wih from LDS) + recurrence ----
    {
      f16x8 ah0 = *rb0k0;
      f16x8 ah1 = *rb0k1;
      const f16x8 xf0 = cvt8h(xa0, xa1);
      const f16x8 xf1 = cvt8h(xb0, xb1);
#pragma unroll
      for (int c = 0; c < 4; ++c) {
        zacc[c] = (f32x4){biasv[c], biasv[c], biasv[c], biasv[c]};
        zacc[c] = __builtin_amdgcn_mfma_f32_16x16x32_f16(xf0, wlds[w][c][0][l], zacc[c], 0, 0, 0);
        zacc[c] = __builtin_amdgcn_mfma_f32_16x16x32_f16(xf1, wlds[w][c][1][l], zacc[c], 0, 0, 0);
      }
      // prefetch x for next pack (stays in flight across barriers)
      if (t0 + 4 < T_STEPS) {
        const int tq = t0 + 4 + q_a;
        const int tm = (tq <= T_STEPS - 1) ? tq : T_STEPS - 1;
        const float* xp = xbase + tm * IN_DIM + g16 * 8;
        xa0 = *(const float4*)xp;
        xa1 = *(const float4*)(xp + 4);
        if (g16 == 0) {
          xb0 = *(const float4*)(xbase + tm * IN_DIM + 32);
          xb1 = *(const float4*)(xbase + tm * IN_DIM + 36);
        }
      }
#pragma unroll
      for (int c = 0; c < 4; ++c) {
        zacc[c] = __builtin_amdgcn_mfma_f32_16x16x32_f16(ah0, whh[c][0], zacc[c], 0, 0, 0);
        zacc[c] = __builtin_amdgcn_mfma_f32_16x16x32_f16(ah1, whh[c][1], zacc[c], 0, 0, 0);
      }
      const float wcn = (t0 + 1 < T_STEPS) ? w_clf[(t0 + 1) * 64 + n] : wc_cur;
      const float h = lstm_act(zacc[0][0], zacc[1][0], zacc[2][0], zacc[3][0], cc);
      a += h * wc_cur;
      wc_cur = wcn;
      union { _Float16 hf; ushort_t u; } cv;
      cv.hf = (_Float16)h;
      hflat[w_q0] = cv.u;
      hflat[z_q0] = 0;
      if (t0 + 1 >= T_STEPS) break;    // t0 == 300 (uniform across block)
      asm volatile("s_waitcnt lgkmcnt(0)\n\ts_barrier" ::: "memory");
    }
    QSTEP(1, rb1k0, rb1k1, w_q1, z_q1)
    QSTEP(2, rb0k0, rb0k1, w_q2, z_q2)
    QSTEP(3, rb1k0, rb1k1, w_q3, z_q3)
  }
#undef QSTEP

  // ---- epilogue: reduce classifier partials over hidden dim ----
  red[n][g16] = a;
  __syncthreads();
  if (tid < 4) {
    float s = b_clf[0];
#pragma unroll 8
    for (int j = 0; j < 64; ++j) s += red[j][tid];
    out[blockIdx.x * 4 + tid] = s;
  }
}

extern "C" void kernel_launch(void* const* d_in, const int* in_sizes, int n_in,
                              void* d_out, int out_size, void* d_ws, size_t ws_size,
                              hipStream_t stream) {
  const float* x     = (const float*)d_in[0];
  const float* w_ih  = (const float*)d_in[1];
  const float* w_hh  = (const float*)d_in[2];
  const float* b_ih  = (const float*)d_in[3];
  const float* b_hh  = (const float*)d_in[4];
  const float* w_clf = (const float*)d_in[5];
  const float* b_clf = (const float*)d_in[6];
  float* out = (float*)d_out;

  lstm_q4t<<<1024, 256, 0, stream>>>(x, w_ih, w_hh, b_ih, b_hh, w_clf, b_clf, out);
}

// Round 17
// 176.811 us; speedup vs baseline: 1.5609x; 1.0811x over previous
//
#include <hip/hip_runtime.h>

#define T_STEPS 301
#define IN_DIM  40
#define LOG2E   1.44269504088896340736f

typedef __attribute__((ext_vector_type(8))) _Float16 f16x8;
typedef __attribute__((ext_vector_type(4))) float f32x4;
typedef unsigned short ushort_t;
typedef unsigned int uint_t;

union u16cv { _Float16 hf; ushort_t u; };

#define MFMA16(A, B, C) __builtin_amdgcn_mfma_f32_16x16x32_f16((A), (B), (C), 0, 0, 0)
#define SGB __builtin_amdgcn_sched_group_barrier

__device__ __forceinline__ f16x8 cvt8h(const float4 a, const float4 b) {
  f16x8 r;
  r[0] = (_Float16)a.x; r[1] = (_Float16)a.y; r[2] = (_Float16)a.z; r[3] = (_Float16)a.w;
  r[4] = (_Float16)b.x; r[5] = (_Float16)b.y; r[6] = (_Float16)b.z; r[7] = (_Float16)b.w;
  return r;
}

// z pre-scaled by log2e (2*log2e for g-gate) -> exp2-based activations.
__device__ __forceinline__ float lstm_act(float zi, float zf, float zg, float zo, float& cc) {
  const float ig = __builtin_amdgcn_rcpf(1.0f + __builtin_amdgcn_exp2f(-zi));
  const float fg = __builtin_amdgcn_rcpf(1.0f + __builtin_amdgcn_exp2f(-zf));
  const float gg = 1.0f - 2.0f * __builtin_amdgcn_rcpf(1.0f + __builtin_amdgcn_exp2f(zg));
  const float og = __builtin_amdgcn_rcpf(1.0f + __builtin_amdgcn_exp2f(-zo));
  cc = fg * cc + ig * gg;
  const float tc = 1.0f - 2.0f * __builtin_amdgcn_rcpf(1.0f + __builtin_amdgcn_exp2f(cc * (2.0f * LOG2E)));
  return og * tc;
}

// R17 = R14 (173.9us: 256 blocks x 256 thr, zero-waste M=16, z/zn ping-pong)
// + sched_group_barrier-forced interleave. R14's failure mode: in-order issue
// means act's trans-stalls (after xproj in program order) can't be filled by
// xproj MFMAs. R17 directs the scheduler: ds_read x2 -> 8 rec MFMA -> then
// 16 x {1 MFMA, 6 VALU} so xproj(t+1) MFMAs thread through act(t)'s VALU/trans
// stream, keeping the matrix pipe busy during the ~500-cyc act region.
__global__ __launch_bounds__(256, 1)
void lstm_sg(const float* __restrict__ x, const float* __restrict__ w_ih,
             const float* __restrict__ w_hh, const float* __restrict__ b_ih,
             const float* __restrict__ b_hh, const float* __restrict__ w_clf,
             const float* __restrict__ b_clf, float* __restrict__ out) {
  extern __shared__ char smem[];
  float*    wclf  = (float*)smem;                       // [301][64], 77056 B
  ushort_t* hflat = (ushort_t*)(smem + 77056);          // [2][16][64], 4096 B
  float*    red   = (float*)(smem + 77056 + 4096);      // [4][16], 256 B

  const int tid = threadIdx.x;
  const int l   = tid & 63, w = tid >> 6;
  const int c15 = l & 15, g16 = l >> 4;
  const int n   = w * 16 + c15;
  const int b0  = blockIdx.x * 16;
  const float gsc[4] = {LOG2E, LOG2E, 2.0f * LOG2E, LOG2E};

  for (int i = tid; i < (T_STEPS * 64) / 4; i += 256)
    ((float4*)wclf)[i] = ((const float4*)w_clf)[i];
  for (int i = tid; i < 1024; i += 256) ((uint_t*)hflat)[i] = 0;

  // ---- weights in registers (fp16, prescaled); bias via k=40 channel ----
  f16x8 whh[4][2], wih[4][2];
#pragma unroll
  for (int g = 0; g < 4; ++g) {
    const float s = gsc[g];
    const float* wr = w_hh + (size_t)(g * 64 + n) * 64;
#pragma unroll
    for (int kc = 0; kc < 2; ++kc) {
      float4 v0 = *(const float4*)(wr + kc * 32 + g16 * 8);
      float4 v1 = *(const float4*)(wr + kc * 32 + g16 * 8 + 4);
      v0.x *= s; v0.y *= s; v0.z *= s; v0.w *= s;
      v1.x *= s; v1.y *= s; v1.z *= s; v1.w *= s;
      whh[g][kc] = cvt8h(v0, v1);
    }
    const float* wi = w_ih + (size_t)(g * 64 + n) * IN_DIM;
    {
      float4 v0 = *(const float4*)(wi + g16 * 8);
      float4 v1 = *(const float4*)(wi + g16 * 8 + 4);
      v0.x *= s; v0.y *= s; v0.z *= s; v0.w *= s;
      v1.x *= s; v1.y *= s; v1.z *= s; v1.w *= s;
      wih[g][0] = cvt8h(v0, v1);
    }
    {
      float4 u0 = make_float4(0, 0, 0, 0), u1 = make_float4(0, 0, 0, 0);
      if (g16 == 0) {
        u0 = *(const float4*)(wi + 32);
        u1 = *(const float4*)(wi + 36);
        u0.x *= s; u0.y *= s; u0.z *= s; u0.w *= s;
        u1.x *= s; u1.y *= s; u1.z *= s; u1.w *= s;
      } else if (g16 == 1) {
        u0.x = (b_ih[g * 64 + n] + b_hh[g * 64 + n]) * s;   // k=40 bias row
      }
      wih[g][1] = cvt8h(u0, u1);
    }
  }
  __syncthreads();

  const int akey = (c15 >> 2) << 4;
  const int ridx0 = c15 * 64 + ((0 * 32 + 8 * g16) ^ akey);
  const int ridx1 = c15 * 64 + ((1 * 32 + 8 * g16) ^ akey);
  int widx[4];
#pragma unroll
  for (int r = 0; r < 4; ++r) widx[r] = (4 * g16 + r) * 64 + (n ^ (g16 << 4));

  const float* xb = x + (size_t)(b0 + c15) * T_STEPS * IN_DIM;
  f16x8 xf1c = {};
  if (g16 == 1) xf1c[0] = (_Float16)1.0f;   // k=40 bias multiplier

  f32x4 z[4], zn[4];
  float cc[4]  = {0.f, 0.f, 0.f, 0.f};
  float acl[4] = {0.f, 0.f, 0.f, 0.f};

  // ---- prologue: xproj(t=0) into z; prefetch x[1] ----
  {
    const float4 v0 = *(const float4*)(xb + g16 * 8);
    const float4 v1 = *(const float4*)(xb + g16 * 8 + 4);
    f16x8 xf0 = cvt8h(v0, v1);
    f16x8 xf1 = xf1c;
    if (g16 == 0) {
      const float4 u0 = *(const float4*)(xb + 32);
      const float4 u1 = *(const float4*)(xb + 36);
      xf1 = cvt8h(u0, u1);
    }
#pragma unroll
    for (int g = 0; g < 4; ++g) {
      f32x4 zz = {0.f, 0.f, 0.f, 0.f};
      zz = MFMA16(xf0, wih[g][0], zz);
      z[g] = MFMA16(xf1, wih[g][1], zz);
    }
  }
  float4 px0, px1, pq0 = make_float4(0, 0, 0, 0), pq1 = make_float4(0, 0, 0, 0);
  {
    const float* xp = xb + IN_DIM;
    px0 = *(const float4*)(xp + g16 * 8);
    px1 = *(const float4*)(xp + g16 * 8 + 4);
    if (g16 == 0) {
      pq0 = *(const float4*)(xp + 32);
      pq1 = *(const float4*)(xp + 36);
    }
  }

  // STEP: rec(t) on ZC; act(t) from ZC; xproj(t+1) into ZN interleaved by SGB.
#define STEP(ZC, ZN, T, LAST)                                                     \
  {                                                                               \
    const int rb = ((T) & 1) * 1024, wb = 1024 - rb;                              \
    f16x8 a0 = *(const f16x8*)(hflat + rb + ridx0);                               \
    f16x8 a1 = *(const f16x8*)(hflat + rb + ridx1);                               \
    _Pragma("unroll")                                                             \
    for (int g = 0; g < 4; ++g) {                                                 \
      ZC[g] = MFMA16(a0, whh[g][0], ZC[g]);                                       \
      ZC[g] = MFMA16(a1, whh[g][1], ZC[g]);                                       \
    }                                                                             \
    if (!(LAST)) {                                                                \
      f16x8 xf0 = cvt8h(px0, px1);                                                \
      f16x8 xf1 = xf1c;                                                           \
      if (g16 == 0) xf1 = cvt8h(pq0, pq1);                                        \
      _Pragma("unroll")                                                           \
      for (int g = 0; g < 4; ++g) {                                               \
        f32x4 zz = {0.f, 0.f, 0.f, 0.f};                                          \
        zz = MFMA16(xf0, wih[g][0], zz);                                          \
        ZN[g] = MFMA16(xf1, wih[g][1], zz);                                       \
      }                                                                           \
      const int tn = ((T) + 2 < T_STEPS) ? (T) + 2 : T_STEPS - 1;                 \
      const float* xp = xb + (size_t)tn * IN_DIM;                                 \
      px0 = *(const float4*)(xp + g16 * 8);                                       \
      px1 = *(const float4*)(xp + g16 * 8 + 4);                                   \
      if (g16 == 0) {                                                             \
        pq0 = *(const float4*)(xp + 32);                                          \
        pq1 = *(const float4*)(xp + 36);                                          \
      }                                                                           \
    }                                                                             \
    const float wc = wclf[(T) * 64 + n];                                          \
    _Pragma("unroll")                                                             \
    for (int r = 0; r < 4; ++r) {                                                 \
      const float h = lstm_act(ZC[0][r], ZC[1][r], ZC[2][r], ZC[3][r], cc[r]);    \
      acl[r] += h * wc;                                                           \
      u16cv cv; cv.hf = (_Float16)h;                                              \
      hflat[wb + widx[r]] = cv.u;                                                 \
    }                                                                             \
    /* forced emission order for this scheduling region:                      */  \
    /* 2 ds_read (a0,a1) -> 8 rec MFMA -> 16 x {1 xproj MFMA, 6 VALU(act)} */     \
    SGB(0x100, 2, 0);                                                             \
    SGB(0x8, 8, 0);                                                               \
    if (!(LAST)) {                                                                \
      _Pragma("unroll")                                                           \
      for (int q = 0; q < 16; ++q) { SGB(0x8, 1, 0); SGB(0x2, 6, 0); }            \
    }                                                                             \
    asm volatile("s_waitcnt lgkmcnt(0)\n\ts_barrier" ::: "memory");               \
  }

  for (int p = 0; p < 150; ++p) {
    const int t0 = 2 * p;
    STEP(z, zn, t0, 0)
    STEP(zn, z, t0 + 1, 0)
  }
  STEP(z, zn, 300, 1)
#undef STEP

  // ---- epilogue: reduce acl over c15 lanes, then across waves ----
#pragma unroll
  for (int m = 1; m <= 8; m <<= 1) {
#pragma unroll
    for (int r = 0; r < 4; ++r) acl[r] += __shfl_xor(acl[r], m);
  }
  if (c15 == 0) {
#pragma unroll
    for (int r = 0; r < 4; ++r) red[w * 16 + 4 * g16 + r] = acl[r];
  }
  __syncthreads();
  if (tid < 16)
    out[b0 + tid] = b_clf[0] + red[tid] + red[16 + tid] + red[32 + tid] + red[48 + tid];
}

extern "C" void kernel_launch(void* const* d_in, const int* in_sizes, int n_in,
                              void* d_out, int out_size, void* d_ws, size_t ws_size,
                              hipStream_t stream) {
  const float* x     = (const float*)d_in[0];
  const float* w_ih  = (const float*)d_in[1];
  const float* w_hh  = (const float*)d_in[2];
  const float* b_ih  = (const float*)d_in[3];
  const float* b_hh  = (const float*)d_in[4];
  const float* w_clf = (const float*)d_in[5];
  const float* b_clf = (const float*)d_in[6];
  float* out = (float*)d_out;

  const size_t shmem = 77056 + 4096 + 256;   // ~79.5 KB dynamic LDS
  (void)hipFuncSetAttribute((const void*)lstm_sg,
                            hipFuncAttributeMaxDynamicSharedMemorySize, (int)shmem);
  lstm_sg<<<256, 256, shmem, stream>>>(x, w_ih, w_hh, b_ih, b_hh, w_clf, b_clf, out);
}